// Round 1
// 406.367 us; speedup vs baseline: 1.0143x; 1.0143x over previous
//
#include <hip/hip_runtime.h>

// HybridSatelliteNormalizer: per-(B,C) channel percentile normalization.
// x: (16,3,1024,1024) fp32. 48 channels x 1,048,576 px each.
//
// Exact k-th-value selection via 2-level histogram (1024 coarse x 1024 fine
// = 2^20 virtual bins), then a streaming apply pass.
//
// This revision: 4 dispatches (memset, hist, refine, apply). The two 48-block
// selection kernels are inlined as per-block scan prologues (redundant across
// blocks, but fully parallel and ~2 us vs. a serialized near-empty dispatch).
// Streaming loops batch 8 float4 loads for MLP; apply uses nontemporal stores
// and reversed chunk order to exploit L3 residency of x from the refine pass.

#define HW (1024 * 1024)
#define NCH 48
#define BPC 32
#define GRID_STREAM (NCH * BPC)              // 1536 blocks
#define F4_PER_BLOCK (HW / BPC / 4)          // 8192 float4 per block
#define F4_PER_THREAD (F4_PER_BLOCK / 256)   // 32 per thread
#define UNROLL 8

typedef float f32x4 __attribute__((ext_vector_type(4)));

// Inclusive prefix-scan of g[0..1023] into LDS s[0..1023]; part = LDS[256]
// temp. 256 threads, ends with a barrier. Safe to call repeatedly with the
// same LDS buffers: callers' reads of s from a prior call happen before this
// call's first barrier, and s is rewritten only after that barrier.
__device__ __forceinline__ void scan1024(const unsigned* __restrict__ g,
                                         unsigned* __restrict__ s,
                                         unsigned* __restrict__ part) {
    const int t = threadIdx.x;
    const uint4 gv = ((const uint4*)g)[t];
    const unsigned p01 = gv.x + gv.y;
    const unsigned p012 = p01 + gv.z;
    const unsigned sum = p012 + gv.w;
    part[t] = sum;
    __syncthreads();
    for (int off = 1; off < 256; off <<= 1) {
        unsigned q = (t >= off) ? part[t - off] : 0u;
        __syncthreads();
        part[t] += q;
        __syncthreads();
    }
    const unsigned excl = (t == 0) ? 0u : part[t - 1];
    s[4 * t + 0] = excl + gv.x;
    s[4 * t + 1] = excl + p01;
    s[4 * t + 2] = excl + p012;
    s[4 * t + 3] = excl + sum;
    __syncthreads();
}

// ---------------- Pass A: coarse histogram (LDS, then global atomics) -------
__global__ __launch_bounds__(256) void k_hist(const float* __restrict__ x,
                                              unsigned* __restrict__ hist) {
    __shared__ unsigned lh[1024];
    const int t = threadIdx.x;
    for (int i = t; i < 1024; i += 256) lh[i] = 0u;
    __syncthreads();

    const int ch = blockIdx.x / BPC;
    const long long base = (long long)blockIdx.x * F4_PER_BLOCK;
    const float4* __restrict__ xv = (const float4*)x + base;

    for (int i = 0; i < F4_PER_THREAD; i += UNROLL) {
        float4 v[UNROLL];
#pragma unroll
        for (int u = 0; u < UNROLL; ++u) v[u] = xv[(i + u) * 256 + t];
#pragma unroll
        for (int u = 0; u < UNROLL; ++u) {
            float f[4] = {v[u].x, v[u].y, v[u].z, v[u].w};
#pragma unroll
            for (int k = 0; k < 4; ++k) {
                if (f[k] > 1e-4f) {
                    int j = (int)(f[k] * 1048576.0f);
                    j = min(j, 1048575);
                    atomicAdd(&lh[j >> 10], 1u);
                }
            }
        }
    }
    __syncthreads();
    unsigned* gh = hist + ch * 1024;
    for (int i = t; i < 1024; i += 256) {
        unsigned c = lh[i];
        if (c) atomicAdd(&gh[i], c);
    }
}

// ---------------- Pass B: inline coarse select + fine sub-histograms --------
__global__ __launch_bounds__(256) void k_refine(const float* __restrict__ x,
                                                const unsigned* __restrict__ hist,
                                                unsigned* __restrict__ sub2,
                                                unsigned* __restrict__ sub98) {
    __shared__ unsigned s[1024];
    __shared__ unsigned part[256];
    __shared__ int sb2, sb98;
    const int t = threadIdx.x;
    const int ch = blockIdx.x / BPC;
    if (t == 0) { sb2 = -2; sb98 = -2; }  // sentinel: never matches a bin

    scan1024(hist + ch * 1024, s, part);
    const int n = (int)s[1023];
    if (n > 0) {
        // reference: k = min(p*n//100 + 1, n); idx = k-1 -> min(p*n/100, n-1)
        const int i2 = min((2 * n) / 100, n - 1);
        const int i98 = min((98 * n) / 100, n - 1);  // 98n < 2^31, fits int32
#pragma unroll
        for (int q = 0; q < 4; ++q) {
            const int b = 4 * t + q;
            const unsigned excl = (b == 0) ? 0u : s[b - 1];
            const unsigned incl = s[b];
            if (excl <= (unsigned)i2 && (unsigned)i2 < incl) sb2 = b;
            if (excl <= (unsigned)i98 && (unsigned)i98 < incl) sb98 = b;
        }
    }
    __syncthreads();
    const int b2 = sb2, b98 = sb98;

    const long long base = (long long)blockIdx.x * F4_PER_BLOCK;
    const float4* __restrict__ xv = (const float4*)x + base;
    unsigned* __restrict__ g2 = sub2 + ch * 1024;
    unsigned* __restrict__ g98 = sub98 + ch * 1024;

    for (int i = 0; i < F4_PER_THREAD; i += UNROLL) {
        float4 v[UNROLL];
#pragma unroll
        for (int u = 0; u < UNROLL; ++u) v[u] = xv[(i + u) * 256 + t];
#pragma unroll
        for (int u = 0; u < UNROLL; ++u) {
            float f[4] = {v[u].x, v[u].y, v[u].z, v[u].w};
#pragma unroll
            for (int k = 0; k < 4; ++k) {
                if (f[k] > 1e-4f) {
                    int j = (int)(f[k] * 1048576.0f);  // identical expr to pass A
                    j = min(j, 1048575);
                    const int cb = j >> 10, fb = j & 1023;
                    if (cb == b2) atomicAdd(&g2[fb], 1u);
                    if (cb == b98) atomicAdd(&g98[fb], 1u);
                }
            }
        }
    }
}

// ---------------- Pass C: inline coarse+fine select + apply -----------------
__device__ __forceinline__ float apply_one(float xx, float mn, float isc,
                                           float mean, float istd) {
    float y = (xx - mn) * isc;
    y = fminf(fmaxf(y, 0.0f), 1.0f);
    // y^(1/2.2) via hw log2/exp2; exactly 0 at y==0 like the reference
    const float g = 0.45454547f;
    float p = (y > 0.0f) ? exp2f(g * log2f(y)) : 0.0f;
    return (p - mean) * istd;
}

__global__ __launch_bounds__(256) void k_apply(const float* __restrict__ x,
                                               float* __restrict__ out,
                                               const unsigned* __restrict__ hist,
                                               const unsigned* __restrict__ sub2,
                                               const unsigned* __restrict__ sub98) {
    __shared__ unsigned s[1024];
    __shared__ unsigned part[256];
    __shared__ int sb2, sr2, sb98, sr98, sf2, sf98;
    const int t = threadIdx.x;
    // reversed chunk order: refine streamed x front-to-back, so the tail of x
    // is the L3-resident part when apply starts; read it first.
    const int rb = GRID_STREAM - 1 - (int)blockIdx.x;
    const int ch = rb / BPC;
    if (t == 0) { sb2 = 0; sr2 = 0; sb98 = 0; sr98 = 0; sf2 = 0; sf98 = 0; }

    scan1024(hist + ch * 1024, s, part);
    const int n = (int)s[1023];
    if (n > 0) {
        const int i2 = min((2 * n) / 100, n - 1);
        const int i98 = min((98 * n) / 100, n - 1);
#pragma unroll
        for (int q = 0; q < 4; ++q) {
            const int b = 4 * t + q;
            const unsigned excl = (b == 0) ? 0u : s[b - 1];
            const unsigned incl = s[b];
            if (excl <= (unsigned)i2 && (unsigned)i2 < incl) { sb2 = b; sr2 = i2 - (int)excl; }
            if (excl <= (unsigned)i98 && (unsigned)i98 < incl) { sb98 = b; sr98 = i98 - (int)excl; }
        }
        __syncthreads();

        scan1024(sub2 + ch * 1024, s, part);
        const int r2 = sr2;
#pragma unroll
        for (int q = 0; q < 4; ++q) {
            const int b = 4 * t + q;
            const unsigned excl = (b == 0) ? 0u : s[b - 1];
            const unsigned incl = s[b];
            if (excl <= (unsigned)r2 && (unsigned)r2 < incl) sf2 = b;
        }
        __syncthreads();

        scan1024(sub98 + ch * 1024, s, part);
        const int r98 = sr98;
#pragma unroll
        for (int q = 0; q < 4; ++q) {
            const int b = 4 * t + q;
            const unsigned excl = (b == 0) ? 0u : s[b - 1];
            const unsigned incl = s[b];
            if (excl <= (unsigned)r98 && (unsigned)r98 < incl) sf98 = b;
        }
    }
    __syncthreads();

    const bool use = n > 100;
    float mn, isc;
    if (use) {
        const float v2 = ((float)(sb2 * 1024 + sf2) + 0.5f) * (1.0f / 1048576.0f);
        const float v98 = ((float)(sb98 * 1024 + sf98) + 0.5f) * (1.0f / 1048576.0f);
        mn = v2;
        isc = 1.0f / fmaxf(v98 - v2, 1e-6f);
    } else {
        mn = 0.0f;
        isc = 1.0f;  // 1/max(1-0, 1e-6)
    }
    const int c3 = ch % 3;
    // explicit selects, not a runtime-indexed array (avoid scratch)
    const float mean = (c3 == 0) ? 0.485f : (c3 == 1) ? 0.456f : 0.406f;
    const float istd = (c3 == 0) ? (1.0f / 0.229f)
                      : (c3 == 1) ? (1.0f / 0.224f) : (1.0f / 0.225f);

    const long long base = (long long)rb * F4_PER_BLOCK;
    const f32x4* __restrict__ xv = (const f32x4*)x + base;
    f32x4* __restrict__ ov = (f32x4*)out + base;

    for (int i = 0; i < F4_PER_THREAD; i += UNROLL) {
        f32x4 v[UNROLL];
#pragma unroll
        for (int u = 0; u < UNROLL; ++u) v[u] = xv[(i + u) * 256 + t];
#pragma unroll
        for (int u = 0; u < UNROLL; ++u) {
            f32x4 r;
            r.x = apply_one(v[u].x, mn, isc, mean, istd);
            r.y = apply_one(v[u].y, mn, isc, mean, istd);
            r.z = apply_one(v[u].z, mn, isc, mean, istd);
            r.w = apply_one(v[u].w, mn, isc, mean, istd);
            __builtin_nontemporal_store(r, &ov[(i + u) * 256 + t]);
        }
    }
}

extern "C" void kernel_launch(void* const* d_in, const int* in_sizes, int n_in,
                              void* d_out, int out_size, void* d_ws, size_t ws_size,
                              hipStream_t stream) {
    const float* x = (const float*)d_in[0];
    float* out = (float*)d_out;

    // workspace: hist 48*1024 u32 | sub2 48*1024 u32 | sub98 48*1024 u32
    unsigned* hist = (unsigned*)d_ws;
    unsigned* sub2 = hist + NCH * 1024;
    unsigned* sub98 = sub2 + NCH * 1024;
    const size_t ws_used = (size_t)(3 * NCH * 1024) * 4;

    hipMemsetAsync(d_ws, 0, ws_used, stream);
    k_hist<<<GRID_STREAM, 256, 0, stream>>>(x, hist);
    k_refine<<<GRID_STREAM, 256, 0, stream>>>(x, hist, sub2, sub98);
    k_apply<<<GRID_STREAM, 256, 0, stream>>>(x, out, hist, sub2, sub98);
}